// Round 4
// baseline (277.230 us; speedup 1.0000x reference)
//
#include <hip/hip_runtime.h>

// LabelLoss: out[b] = sum_{n,c<7} (pred[b,n,c] - gt[b,n,c])^2
// pred/gt: [256, 16384, 8] fp32. R1-R3 all land at ~2.7 TB/s effective read
// BW: compiler pins the schedule at 32 VGPRs (~4 loads in flight) and every
// wave drains to 0 outstanding loads at each consume + block tail -> poor
// memory duty cycle. R4: explicit double-buffered software pipeline. Each
// block streams 8 chunks; load chunk c+1 before consuming chunk c, so >=8
// dwordx4 loads stay in flight per wave for the whole kernel. Tail
// (reduce+atomic) amortized over 64 loads/thread.

#define THREADS 256
#define SPLIT 4                               // blocks per batch row
#define F4_PER_BATCH (16384 * 2)              // 32768 float4s per batch per input
#define F4_PER_BLOCK (F4_PER_BATCH / SPLIT)   // 8192
#define DEPTH 4                               // float4s per thread per chunk
#define CHUNK (THREADS * DEPTH)               // 1024 float4s per chunk
#define NCHUNK (F4_PER_BLOCK / CHUNK)         // 8 chunks per block

__global__ __launch_bounds__(THREADS) void label_loss_kernel(
    const float4* __restrict__ pred,
    const float4* __restrict__ gt,
    float* __restrict__ out)
{
    const int b   = blockIdx.x / SPLIT;
    const int seg = blockIdx.x % SPLIT;
    const long base = (long)b * F4_PER_BATCH + (long)seg * F4_PER_BLOCK
                    + threadIdx.x;

    // Channel-7 mask: float4 index parity == tid&1 (all strides even):
    // lane-uniform, no divergence.
    const float m = (threadIdx.x & 1) ? 0.0f : 1.0f;

    float4 Pa[DEPTH], Ga[DEPTH], Pb[DEPTH], Gb[DEPTH];
    float acc[DEPTH] = {0.0f, 0.0f, 0.0f, 0.0f};

#define LOAD(P_, G_, c) do {                                          \
    const long o_ = base + (long)(c) * CHUNK;                         \
    _Pragma("unroll")                                                 \
    for (int k = 0; k < DEPTH; ++k) P_[k] = pred[o_ + k * THREADS];   \
    _Pragma("unroll")                                                 \
    for (int k = 0; k < DEPTH; ++k) G_[k] = gt[o_ + k * THREADS];     \
  } while (0)

#define CONSUME(P_, G_) do {                                          \
    _Pragma("unroll")                                                 \
    for (int k = 0; k < DEPTH; ++k) {                                 \
      const float dx = P_[k].x - G_[k].x;                             \
      const float dy = P_[k].y - G_[k].y;                             \
      const float dz = P_[k].z - G_[k].z;                             \
      const float dw = P_[k].w - G_[k].w;                             \
      acc[k] += dx * dx + dy * dy + dz * dz + m * (dw * dw);          \
    }                                                                 \
  } while (0)

    // Prologue: chunk 0 in flight.
    LOAD(Pa, Ga, 0);

    // Steady state: always >= one chunk (8 loads) outstanding.
    #pragma unroll 1
    for (int c = 0; c + 2 < NCHUNK; c += 2) {
        LOAD(Pb, Gb, c + 1);
        CONSUME(Pa, Ga);
        LOAD(Pa, Ga, c + 2);
        CONSUME(Pb, Gb);
    }
    // Epilogue: Pa holds chunk NCHUNK-2; chunk NCHUNK-1 not yet loaded.
    LOAD(Pb, Gb, NCHUNK - 1);
    CONSUME(Pa, Ga);
    CONSUME(Pb, Gb);

#undef LOAD
#undef CONSUME

    float v = (acc[0] + acc[1]) + (acc[2] + acc[3]);

    // 64-lane wave reduction
    #pragma unroll
    for (int off = 32; off > 0; off >>= 1)
        v += __shfl_down(v, off, 64);

    __shared__ float wsum[THREADS / 64];
    const int lane = threadIdx.x & 63;
    const int wave = threadIdx.x >> 6;
    if (lane == 0) wsum[wave] = v;
    __syncthreads();

    if (threadIdx.x == 0) {
        atomicAdd(&out[b], wsum[0] + wsum[1] + wsum[2] + wsum[3]);
    }
}

extern "C" void kernel_launch(void* const* d_in, const int* in_sizes, int n_in,
                              void* d_out, int out_size, void* d_ws, size_t ws_size,
                              hipStream_t stream) {
    const float4* pred = (const float4*)d_in[0];
    const float4* gt   = (const float4*)d_in[1];
    float* out = (float*)d_out;

    // d_out is re-poisoned to 0xAA before every launch; we accumulate with
    // atomics, so zero it first (async memset is graph-capture safe).
    hipMemsetAsync(d_out, 0, (size_t)out_size * sizeof(float), stream);

    const int n_blocks = 256 * SPLIT;  // 1024 blocks, 4 resident per CU
    label_loss_kernel<<<dim3(n_blocks), dim3(THREADS), 0, stream>>>(pred, gt, out);
}

// Round 6
// 248.884 us; speedup vs baseline: 1.1139x; 1.1139x over previous
//
#include <hip/hip_runtime.h>

// LabelLoss: out[b] = sum_{n,c<7} (pred[b,n,c] - gt[b,n,c])^2
// pred/gt: [256, 16384, 8] fp32. R1-R4: four structurally different kernels
// (loop / unroll4 / straight-8 / double-buffered pipeline, 12-60 VGPRs,
// 1024-4096 blocks) ALL land at ~100 us = 2.68 TB/s read = 10.5 GB/s/CU.
// Little's law rules out latency-bound; HBM/VALU/LDS all idle. Best-known
// read rates on this chip cluster at 10-12 GB/s/CU (m13 copy reads 12.3,
// m146 RMSNorm reads ~9.5) -> per-CU L1/TCP read-service (MSHR) ceiling.
// R6 = R5 with the compile fix: __builtin_nontemporal_load requires a
// native clang vector type, not HIP_vector_type -> use ext_vector_type(4).

#define THREADS 256
#define SPLIT 8                               // blocks per batch row
#define F4_PER_BATCH (16384 * 2)              // 32768 float4s per batch per input
#define F4_PER_BLOCK (F4_PER_BATCH / SPLIT)   // 4096
#define UNROLL 4
#define OUTER (F4_PER_BLOCK / (THREADS * UNROLL))  // 4

typedef float vfloat4 __attribute__((ext_vector_type(4)));

__global__ __launch_bounds__(THREADS) void label_loss_kernel(
    const vfloat4* __restrict__ pred,
    const vfloat4* __restrict__ gt,
    float* __restrict__ out)
{
    const int bx  = blockIdx.x;
    const int b   = bx / SPLIT;
    const int seg = bx % SPLIT;
    const long base = (long)b * F4_PER_BATCH + (long)seg * F4_PER_BLOCK;

    // Channel-7 mask: float4 index parity == tid&1 (all strides even):
    // lane-uniform, no divergence.
    const float m = (threadIdx.x & 1) ? 0.0f : 1.0f;

    float acc0 = 0.0f, acc1 = 0.0f, acc2 = 0.0f, acc3 = 0.0f;

    #pragma unroll 1
    for (int it = 0; it < OUTER; ++it) {
        const long i0 = base + (long)it * (THREADS * UNROLL) + threadIdx.x;
        // Non-temporal: no L1 allocation (data has zero reuse).
        const vfloat4 p0 = __builtin_nontemporal_load(&pred[i0]);
        const vfloat4 p1 = __builtin_nontemporal_load(&pred[i0 + 256]);
        const vfloat4 p2 = __builtin_nontemporal_load(&pred[i0 + 512]);
        const vfloat4 p3 = __builtin_nontemporal_load(&pred[i0 + 768]);
        const vfloat4 g0 = __builtin_nontemporal_load(&gt[i0]);
        const vfloat4 g1 = __builtin_nontemporal_load(&gt[i0 + 256]);
        const vfloat4 g2 = __builtin_nontemporal_load(&gt[i0 + 512]);
        const vfloat4 g3 = __builtin_nontemporal_load(&gt[i0 + 768]);

        vfloat4 d;
        d = p0 - g0;
        acc0 += d.x * d.x + d.y * d.y + d.z * d.z + m * (d.w * d.w);
        d = p1 - g1;
        acc1 += d.x * d.x + d.y * d.y + d.z * d.z + m * (d.w * d.w);
        d = p2 - g2;
        acc2 += d.x * d.x + d.y * d.y + d.z * d.z + m * (d.w * d.w);
        d = p3 - g3;
        acc3 += d.x * d.x + d.y * d.y + d.z * d.z + m * (d.w * d.w);
    }

    float v = (acc0 + acc1) + (acc2 + acc3);

    // 64-lane wave reduction
    #pragma unroll
    for (int off = 32; off > 0; off >>= 1)
        v += __shfl_down(v, off, 64);

    __shared__ float wsum[THREADS / 64];
    const int lane = threadIdx.x & 63;
    const int wave = threadIdx.x >> 6;
    if (lane == 0) wsum[wave] = v;
    __syncthreads();

    if (threadIdx.x == 0) {
        atomicAdd(&out[b], wsum[0] + wsum[1] + wsum[2] + wsum[3]);
    }
}

extern "C" void kernel_launch(void* const* d_in, const int* in_sizes, int n_in,
                              void* d_out, int out_size, void* d_ws, size_t ws_size,
                              hipStream_t stream) {
    const vfloat4* pred = (const vfloat4*)d_in[0];
    const vfloat4* gt   = (const vfloat4*)d_in[1];
    float* out = (float*)d_out;

    // d_out is re-poisoned to 0xAA before every launch; we accumulate with
    // atomics, so zero it first (async memset is graph-capture safe).
    (void)hipMemsetAsync(d_out, 0, (size_t)out_size * sizeof(float), stream);

    const int n_blocks = 256 * SPLIT;  // 2048 blocks, 8 per CU
    label_loss_kernel<<<dim3(n_blocks), dim3(THREADS), 0, stream>>>(pred, gt, out);
}

// Round 7
// 248.667 us; speedup vs baseline: 1.1149x; 1.0009x over previous
//
#include <hip/hip_runtime.h>

// LabelLoss: out[b] = sum_{n,c<7} (pred[b,n,c] - gt[b,n,c])^2
// pred/gt: [256, 16384, 8] fp32.
// History: R1-R4 all ~100 us (2.7 TB/s read) regardless of structure ->
// per-CU L1/TCP read-service ceiling. R6: nontemporal loads (L1 bypass)
// -> ~75 us (~3.6 TB/s). R7: now that L1 allocation is out of the path,
// re-apply the explicit double-buffered pipeline so each wave keeps 8 nt
// dwordx4 loads in flight continuously (R4 showed the structure compiles
// to ~60 VGPRs with true batched loads; it was neutral then only because
// the TCP cap gated everything).

#define THREADS 256
#define SPLIT 8                               // blocks per batch row
#define F4_PER_BATCH (16384 * 2)              // 32768 float4s per batch per input
#define F4_PER_BLOCK (F4_PER_BATCH / SPLIT)   // 4096
#define DEPTH 4                               // float4s per thread per chunk
#define CHUNK (THREADS * DEPTH)               // 1024 float4s per chunk
#define NCHUNK (F4_PER_BLOCK / CHUNK)         // 4 chunks per block

typedef float vfloat4 __attribute__((ext_vector_type(4)));

__global__ __launch_bounds__(THREADS) void label_loss_kernel(
    const vfloat4* __restrict__ pred,
    const vfloat4* __restrict__ gt,
    float* __restrict__ out)
{
    const int b   = blockIdx.x / SPLIT;
    const int seg = blockIdx.x % SPLIT;
    const long base = (long)b * F4_PER_BATCH + (long)seg * F4_PER_BLOCK
                    + threadIdx.x;

    // Channel-7 mask: float4 index parity == tid&1 (all strides even):
    // lane-uniform, no divergence.
    const float m = (threadIdx.x & 1) ? 0.0f : 1.0f;

    vfloat4 Pa[DEPTH], Ga[DEPTH], Pb[DEPTH], Gb[DEPTH];
    float acc[DEPTH] = {0.0f, 0.0f, 0.0f, 0.0f};

#define LOAD(P_, G_, c) do {                                              \
    const long o_ = base + (long)(c) * CHUNK;                             \
    _Pragma("unroll")                                                     \
    for (int k = 0; k < DEPTH; ++k)                                       \
      P_[k] = __builtin_nontemporal_load(&pred[o_ + k * THREADS]);        \
    _Pragma("unroll")                                                     \
    for (int k = 0; k < DEPTH; ++k)                                       \
      G_[k] = __builtin_nontemporal_load(&gt[o_ + k * THREADS]);          \
  } while (0)

#define CONSUME(P_, G_) do {                                              \
    _Pragma("unroll")                                                     \
    for (int k = 0; k < DEPTH; ++k) {                                     \
      const vfloat4 d_ = P_[k] - G_[k];                                   \
      acc[k] += d_.x * d_.x + d_.y * d_.y + d_.z * d_.z + m * (d_.w * d_.w); \
    }                                                                     \
  } while (0)

    // Prologue: chunk 0 in flight.
    LOAD(Pa, Ga, 0);

    // Steady state: always >= one chunk (8 nt loads) outstanding.
    #pragma unroll 1
    for (int c = 0; c + 2 < NCHUNK; c += 2) {
        LOAD(Pb, Gb, c + 1);
        CONSUME(Pa, Ga);
        LOAD(Pa, Ga, c + 2);
        CONSUME(Pb, Gb);
    }
    // Epilogue: Pa holds chunk NCHUNK-2 (NCHUNK is even).
    LOAD(Pb, Gb, NCHUNK - 1);
    CONSUME(Pa, Ga);
    CONSUME(Pb, Gb);

#undef LOAD
#undef CONSUME

    float v = (acc[0] + acc[1]) + (acc[2] + acc[3]);

    // 64-lane wave reduction
    #pragma unroll
    for (int off = 32; off > 0; off >>= 1)
        v += __shfl_down(v, off, 64);

    __shared__ float wsum[THREADS / 64];
    const int lane = threadIdx.x & 63;
    const int wave = threadIdx.x >> 6;
    if (lane == 0) wsum[wave] = v;
    __syncthreads();

    if (threadIdx.x == 0) {
        atomicAdd(&out[b], wsum[0] + wsum[1] + wsum[2] + wsum[3]);
    }
}

extern "C" void kernel_launch(void* const* d_in, const int* in_sizes, int n_in,
                              void* d_out, int out_size, void* d_ws, size_t ws_size,
                              hipStream_t stream) {
    const vfloat4* pred = (const vfloat4*)d_in[0];
    const vfloat4* gt   = (const vfloat4*)d_in[1];
    float* out = (float*)d_out;

    // d_out is re-poisoned to 0xAA before every launch; we accumulate with
    // atomics, so zero it first (async memset is graph-capture safe).
    (void)hipMemsetAsync(d_out, 0, (size_t)out_size * sizeof(float), stream);

    const int n_blocks = 256 * SPLIT;  // 2048 blocks, 8 per CU
    label_loss_kernel<<<dim3(n_blocks), dim3(THREADS), 0, stream>>>(pred, gt, out);
}